// Round 14
// baseline (858.727 us; speedup 1.0000x reference)
//
#include <hip/hip_runtime.h>

#define DIM 64
#define NPB 256          // nodes per bucket (bucket id = dst >> 8)
#define MAXBUCK 512      // N up to 131072
#define CHUNK 4096       // edges per binning block

__device__ __forceinline__ unsigned short f2bf(float v) {
    unsigned u = __float_as_uint(v);
    unsigned r = (u + 0x7fffu + ((u >> 16) & 1u)) >> 16;  // RNE
    return (unsigned short)r;
}

// h = x @ W -> bf16. Register-tiled: thread = 2 nodes x 4 dims.
// Per k: 1 ds_read_b128 (W row seg) + 2 broadcast b32 (x) + 8 FMA.
__global__ void gcn_matmul(const float* __restrict__ x, const float* __restrict__ W,
                           unsigned short* __restrict__ hbf, int N) {
    __shared__ float Wl[DIM * DIM];    // 16 KB, row-major [k][d]
    __shared__ float xs[32][68];       // 8.7 KB, padded rows (bank spread)
    int tid = threadIdx.x;
    for (int i = tid; i < 1024; i += 256)
        ((float4*)Wl)[i] = ((const float4*)W)[i];
    int node0 = blockIdx.x * 32;
    for (int i = tid; i < 512; i += 256) {
        int n = i >> 4, c4 = (i & 15) * 4;
        int gn = node0 + n;
        float4 v;
        if (gn < N) v = *(const float4*)(x + (long)gn * DIM + c4);
        else { v.x = v.y = v.z = v.w = 0.f; }
        *(float4*)&xs[n][c4] = v;
    }
    __syncthreads();

    int lane = tid & 63, wv_ = tid >> 6;
    int d4 = (lane & 15) * 4;
    int g = lane >> 4;
    int n0 = wv_ * 8 + g * 2, n1 = n0 + 1;
    float4 a0, a1;
    a0.x = a0.y = a0.z = a0.w = 0.f;
    a1.x = a1.y = a1.z = a1.w = 0.f;
#pragma unroll
    for (int k = 0; k < DIM; ++k) {
        float4 wr = *(const float4*)&Wl[k * DIM + d4];
        float xa = xs[n0][k];
        float xb = xs[n1][k];
        a0.x += xa * wr.x; a0.y += xa * wr.y; a0.z += xa * wr.z; a0.w += xa * wr.w;
        a1.x += xb * wr.x; a1.y += xb * wr.y; a1.z += xb * wr.z; a1.w += xb * wr.w;
    }
    int gn0 = node0 + n0, gn1 = node0 + n1;
    if (gn0 < N) {
        uint2 p;
        p.x = (unsigned)f2bf(a0.x) | ((unsigned)f2bf(a0.y) << 16);
        p.y = (unsigned)f2bf(a0.z) | ((unsigned)f2bf(a0.w) << 16);
        *(uint2*)(hbf + (long)gn0 * DIM + d4) = p;
    }
    if (gn1 < N) {
        uint2 p;
        p.x = (unsigned)f2bf(a1.x) | ((unsigned)f2bf(a1.y) << 16);
        p.y = (unsigned)f2bf(a1.z) | ((unsigned)f2bf(a1.w) << 16);
        *(uint2*)(hbf + (long)gn1 * DIM + d4) = p;
    }
}

__global__ void zero_i32(int* __restrict__ p, int n) {
    int i = blockIdx.x * 256 + threadIdx.x;
    if (i < n) p[i] = 0;
}

// bucket histogram only (LDS-aggregated)
__global__ void count_buckets(const int* __restrict__ ei, int* __restrict__ bcount,
                              int E, int nbuck) {
    __shared__ int hist[MAXBUCK];
    int tid = threadIdx.x;
    for (int i = tid; i < nbuck; i += 256) hist[i] = 0;
    __syncthreads();
    for (long e = (long)blockIdx.x * 256 + tid; e < E; e += (long)gridDim.x * 256)
        atomicAdd(&hist[ei[E + e] >> 8], 1);
    __syncthreads();
    for (int i = tid; i < nbuck; i += 256)
        if (hist[i]) atomicAdd(&bcount[i], hist[i]);
}

// single-block exclusive scan of bucket counts -> boff, init bcur
__global__ void scan_buckets(const int* __restrict__ bcount, int* __restrict__ boff,
                             int* __restrict__ bcur, int nbuck, int E) {
    __shared__ int sh[MAXBUCK];
    int tid = threadIdx.x;  // 512
    int v = (tid < nbuck) ? bcount[tid] : 0;
    sh[tid] = v;
    __syncthreads();
    for (int d = 1; d < MAXBUCK; d <<= 1) {
        int t = (tid >= d) ? sh[tid - d] : 0;
        __syncthreads();
        sh[tid] += t;
        __syncthreads();
    }
    if (tid < nbuck) {
        int o = sh[tid] - v;
        boff[tid] = o;
        bcur[tid] = o;
    }
    if (tid == 0) boff[nbuck] = E;
}

// phase A: bin edges into bucket-contiguous storage; entry = (src<<8) | (dst&255)
__global__ void bin_edges(const int* __restrict__ ei, int* __restrict__ bcur,
                          unsigned* __restrict__ binned, int E, int nbuck) {
    __shared__ int hist[MAXBUCK];
    int tid = threadIdx.x;
    long e0 = (long)blockIdx.x * CHUNK;
    for (int i = tid; i < nbuck; i += 256) hist[i] = 0;
    __syncthreads();
    int s[16], t[16];
#pragma unroll
    for (int it = 0; it < 16; ++it) {
        long e = e0 + it * 256 + tid;
        if (e < E) {
            s[it] = ei[e];
            t[it] = ei[E + e];
            atomicAdd(&hist[t[it] >> 8], 1);
        } else {
            s[it] = -1;
        }
    }
    __syncthreads();
    for (int i = tid; i < nbuck; i += 256) {
        int c = hist[i];
        hist[i] = c ? atomicAdd(&bcur[i], c) : 0;
    }
    __syncthreads();
#pragma unroll
    for (int it = 0; it < 16; ++it) {
        if (s[it] >= 0) {
            int b = t[it] >> 8;
            int p = atomicAdd(&hist[b], 1);
            binned[p] = ((unsigned)s[it] << 8) | (unsigned)(t[it] & 255);
        }
    }
}

// phase B: per-bucket LDS counting sort -> per-node CSR (adj, rowptr off, dinv)
__global__ void bucket_sort(const int* __restrict__ boff, const unsigned* __restrict__ binned,
                            int* __restrict__ off, int* __restrict__ adj,
                            float* __restrict__ dinv, int N, int E) {
    __shared__ int lcur[NPB];
    __shared__ int sh[NPB];
    int bid = blockIdx.x, tid = threadIdx.x;  // 256 threads
    int node0 = bid << 8;
    int e0 = boff[bid], e1 = boff[bid + 1];
    lcur[tid] = 0;
    __syncthreads();
    for (int e = e0 + tid; e < e1; e += 256)
        atomicAdd(&lcur[binned[e] & 255], 1);
    __syncthreads();
    int v = lcur[tid];
    sh[tid] = v;
    __syncthreads();
    for (int d = 1; d < NPB; d <<= 1) {
        int t = (tid >= d) ? sh[tid - d] : 0;
        __syncthreads();
        sh[tid] += t;
        __syncthreads();
    }
    int excl = sh[tid] - v;
    __syncthreads();
    lcur[tid] = excl;
    int node = node0 + tid;
    if (node < N) {
        off[node] = e0 + excl;
        dinv[node] = rsqrtf((float)v + 1.0f);
    }
    if (tid == 0 && bid == gridDim.x - 1) off[N] = E;
    __syncthreads();
    for (int e = e0 + tid; e < e1; e += 256) {
        unsigned u = binned[e];
        int p = atomicAdd(&lcur[u & 255], 1);
        adj[e0 + p] = (int)(u >> 8);
    }
}

// one wave per node; 2 edges per load instruction (bf16 rows), 8 loads in flight.
// lane = (sub = lane>>5 selects edge-of-pair, f = lane&31 selects feature pair)
__global__ void gather_agg(const int* __restrict__ off, const int* __restrict__ adj,
                           const unsigned* __restrict__ hb, const float* __restrict__ dinv,
                           const float2* __restrict__ x2, const float2* __restrict__ b2,
                           float2* __restrict__ o2, int N) {
    int node = blockIdx.x * 4 + (threadIdx.x >> 6);
    int lane = threadIdx.x & 63;
    if (node >= N) return;
    int sub = lane >> 5;     // which edge of the pair
    int f = lane & 31;       // feature-pair index (features 2f, 2f+1)
    int start = off[node];
    int m = off[node + 1] - start;
    float dn = dinv[node];
    float2 acc; acc.x = 0.f; acc.y = 0.f;

    for (int c = 0; c < m; c += 64) {
        int rem = m - c;
        int take = rem < 64 ? rem : 64;
        int s = (lane < take) ? adj[start + c + lane] : 0;
        float w = (lane < take) ? dinv[s] : 0.f;
        for (int i = 0; i < take; i += 16) {
            int i0 = i + 0 + sub,  i1 = i + 2 + sub,  i2 = i + 4 + sub,  i3 = i + 6 + sub;
            int i4 = i + 8 + sub,  i5 = i + 10 + sub, i6 = i + 12 + sub, i7 = i + 14 + sub;
            int t0 = __shfl(s, i0), t1 = __shfl(s, i1), t2 = __shfl(s, i2), t3 = __shfl(s, i3);
            int t4 = __shfl(s, i4), t5 = __shfl(s, i5), t6 = __shfl(s, i6), t7 = __shfl(s, i7);
            float q0 = __shfl(w, i0), q1 = __shfl(w, i1), q2 = __shfl(w, i2), q3 = __shfl(w, i3);
            float q4 = __shfl(w, i4), q5 = __shfl(w, i5), q6 = __shfl(w, i6), q7 = __shfl(w, i7);
            unsigned u0 = hb[(long)t0 * 32 + f];
            unsigned u1 = hb[(long)t1 * 32 + f];
            unsigned u2 = hb[(long)t2 * 32 + f];
            unsigned u3 = hb[(long)t3 * 32 + f];
            unsigned u4 = hb[(long)t4 * 32 + f];
            unsigned u5 = hb[(long)t5 * 32 + f];
            unsigned u6 = hb[(long)t6 * 32 + f];
            unsigned u7 = hb[(long)t7 * 32 + f];
            acc.x += __uint_as_float(u0 << 16) * q0;
            acc.y += __uint_as_float(u0 & 0xffff0000u) * q0;
            acc.x += __uint_as_float(u1 << 16) * q1;
            acc.y += __uint_as_float(u1 & 0xffff0000u) * q1;
            acc.x += __uint_as_float(u2 << 16) * q2;
            acc.y += __uint_as_float(u2 & 0xffff0000u) * q2;
            acc.x += __uint_as_float(u3 << 16) * q3;
            acc.y += __uint_as_float(u3 & 0xffff0000u) * q3;
            acc.x += __uint_as_float(u4 << 16) * q4;
            acc.y += __uint_as_float(u4 & 0xffff0000u) * q4;
            acc.x += __uint_as_float(u5 << 16) * q5;
            acc.y += __uint_as_float(u5 & 0xffff0000u) * q5;
            acc.x += __uint_as_float(u6 << 16) * q6;
            acc.y += __uint_as_float(u6 & 0xffff0000u) * q6;
            acc.x += __uint_as_float(u7 << 16) * q7;
            acc.y += __uint_as_float(u7 & 0xffff0000u) * q7;
        }
    }
    // merge the two half-wave edge sums (lane <-> lane^32)
    acc.x += __shfl_xor(acc.x, 32);
    acc.y += __shfl_xor(acc.y, 32);
    // self loop (post-merge, once)
    unsigned us = hb[(long)node * 32 + f];
    acc.x += __uint_as_float(us << 16) * dn;
    acc.y += __uint_as_float(us & 0xffff0000u) * dn;

    if (lane < 32) {
        long gi = (long)node * 32 + f;
        float2 bb = b2[f];
        float2 xx = x2[gi];
        float2 r;
        float vx = acc.x * dn + bb.x;
        float vy = acc.y * dn + bb.y;
        r.x = xx.x + fmaxf(vx, 0.f);
        r.y = xx.y + fmaxf(vy, 0.f);
        o2[gi] = r;
    }
}

extern "C" void kernel_launch(void* const* d_in, const int* in_sizes, int n_in,
                              void* d_out, int out_size, void* d_ws, size_t ws_size,
                              hipStream_t stream) {
    const float* x = (const float*)d_in[0];
    const int* ei  = (const int*)d_in[1];
    const float* W = (const float*)d_in[2];
    const float* b = (const float*)d_in[3];
    float* out = (float*)d_out;

    int N = in_sizes[0] / DIM;
    int E = in_sizes[1] / 2;
    int nbuck = (N + NPB - 1) / NPB;  // 391

    char* ws = (char*)d_ws;
    size_t o = 0;
    unsigned short* hbf = (unsigned short*)(ws + o); o += (size_t)N * DIM * sizeof(unsigned short);
    float* dinv  = (float*)(ws + o); o += (size_t)N * sizeof(float);
    int*   off   = (int*)(ws + o);   o += (size_t)(N + 1) * sizeof(int);
    int*   bcount= (int*)(ws + o);   o += (size_t)nbuck * sizeof(int);
    int*   boff  = (int*)(ws + o);   o += (size_t)(nbuck + 1) * sizeof(int);
    int*   bcur  = (int*)(ws + o);   o += (size_t)nbuck * sizeof(int);
    unsigned* binned = (unsigned*)(ws + o); o += (size_t)E * sizeof(unsigned);
    int*   adj   = (int*)(ws + o);   o += (size_t)E * sizeof(int);

    gcn_matmul<<<(N + 31) / 32, 256, 0, stream>>>(x, W, hbf, N);
    zero_i32<<<(nbuck + 255) / 256, 256, 0, stream>>>(bcount, nbuck);
    count_buckets<<<512, 256, 0, stream>>>(ei, bcount, E, nbuck);
    scan_buckets<<<1, MAXBUCK, 0, stream>>>(bcount, boff, bcur, nbuck, E);
    bin_edges<<<(E + CHUNK - 1) / CHUNK, 256, 0, stream>>>(ei, bcur, binned, E, nbuck);
    bucket_sort<<<nbuck, 256, 0, stream>>>(boff, binned, off, adj, dinv, N, E);
    gather_agg<<<(N + 3) / 4, 256, 0, stream>>>(off, adj, (const unsigned*)hbf, dinv,
                                                (const float2*)x, (const float2*)b,
                                                (float2*)out, N);
}

// Round 15
// 127.640 us; speedup vs baseline: 6.7277x; 6.7277x over previous
//
#include <hip/hip_runtime.h>

#define DIM 64
#define NPB 256          // nodes per bucket (bucket id = dst >> 8)
#define MAXBUCK 512      // N up to 131072
#define CHUNK 4096       // edges per binning block

__device__ __forceinline__ unsigned short f2bf(float v) {
    unsigned u = __float_as_uint(v);
    unsigned r = (u + 0x7fffu + ((u >> 16) & 1u)) >> 16;  // RNE
    return (unsigned short)r;
}

// h = x @ W -> bf16. Register-tiled: thread = 2 nodes x 4 dims.
// Per k: 1 ds_read_b128 (W row seg) + 2 broadcast b32 (x) + 8 FMA.
// unroll capped at 4: full unroll hoisted ~64 float4 LDS temps -> scratch
// spill (1.04 GB FETCH/dispatch, R14). 4x keeps live set ~32 VGPRs.
__global__ void gcn_matmul(const float* __restrict__ x, const float* __restrict__ W,
                           unsigned short* __restrict__ hbf, int N) {
    __shared__ float Wl[DIM * DIM];    // 16 KB, row-major [k][d]
    __shared__ float xs[32][68];       // 8.7 KB, padded rows (bank spread)
    int tid = threadIdx.x;
    for (int i = tid; i < 1024; i += 256)
        ((float4*)Wl)[i] = ((const float4*)W)[i];
    int node0 = blockIdx.x * 32;
    for (int i = tid; i < 512; i += 256) {
        int n = i >> 4, c4 = (i & 15) * 4;
        int gn = node0 + n;
        float4 v;
        if (gn < N) v = *(const float4*)(x + (long)gn * DIM + c4);
        else { v.x = v.y = v.z = v.w = 0.f; }
        *(float4*)&xs[n][c4] = v;
    }
    __syncthreads();

    int lane = tid & 63, wv_ = tid >> 6;
    int d4 = (lane & 15) * 4;
    int g = lane >> 4;
    int n0 = wv_ * 8 + g * 2, n1 = n0 + 1;
    float4 a0, a1;
    a0.x = a0.y = a0.z = a0.w = 0.f;
    a1.x = a1.y = a1.z = a1.w = 0.f;
#pragma unroll 4
    for (int k = 0; k < DIM; ++k) {
        float4 wr = *(const float4*)&Wl[k * DIM + d4];
        float xa = xs[n0][k];
        float xb = xs[n1][k];
        a0.x += xa * wr.x; a0.y += xa * wr.y; a0.z += xa * wr.z; a0.w += xa * wr.w;
        a1.x += xb * wr.x; a1.y += xb * wr.y; a1.z += xb * wr.z; a1.w += xb * wr.w;
    }
    int gn0 = node0 + n0, gn1 = node0 + n1;
    if (gn0 < N) {
        uint2 p;
        p.x = (unsigned)f2bf(a0.x) | ((unsigned)f2bf(a0.y) << 16);
        p.y = (unsigned)f2bf(a0.z) | ((unsigned)f2bf(a0.w) << 16);
        *(uint2*)(hbf + (long)gn0 * DIM + d4) = p;
    }
    if (gn1 < N) {
        uint2 p;
        p.x = (unsigned)f2bf(a1.x) | ((unsigned)f2bf(a1.y) << 16);
        p.y = (unsigned)f2bf(a1.z) | ((unsigned)f2bf(a1.w) << 16);
        *(uint2*)(hbf + (long)gn1 * DIM + d4) = p;
    }
}

__global__ void zero_i32(int* __restrict__ p, int n) {
    int i = blockIdx.x * 256 + threadIdx.x;
    if (i < n) p[i] = 0;
}

// bucket histogram only (LDS-aggregated)
__global__ void count_buckets(const int* __restrict__ ei, int* __restrict__ bcount,
                              int E, int nbuck) {
    __shared__ int hist[MAXBUCK];
    int tid = threadIdx.x;
    for (int i = tid; i < nbuck; i += 256) hist[i] = 0;
    __syncthreads();
    for (long e = (long)blockIdx.x * 256 + tid; e < E; e += (long)gridDim.x * 256)
        atomicAdd(&hist[ei[E + e] >> 8], 1);
    __syncthreads();
    for (int i = tid; i < nbuck; i += 256)
        if (hist[i]) atomicAdd(&bcount[i], hist[i]);
}

// single-block exclusive scan of bucket counts -> boff, init bcur
__global__ void scan_buckets(const int* __restrict__ bcount, int* __restrict__ boff,
                             int* __restrict__ bcur, int nbuck, int E) {
    __shared__ int sh[MAXBUCK];
    int tid = threadIdx.x;  // 512
    int v = (tid < nbuck) ? bcount[tid] : 0;
    sh[tid] = v;
    __syncthreads();
    for (int d = 1; d < MAXBUCK; d <<= 1) {
        int t = (tid >= d) ? sh[tid - d] : 0;
        __syncthreads();
        sh[tid] += t;
        __syncthreads();
    }
    if (tid < nbuck) {
        int o = sh[tid] - v;
        boff[tid] = o;
        bcur[tid] = o;
    }
    if (tid == 0) boff[nbuck] = E;
}

// phase A: bin edges into bucket-contiguous storage; entry = (src<<8) | (dst&255)
__global__ void bin_edges(const int* __restrict__ ei, int* __restrict__ bcur,
                          unsigned* __restrict__ binned, int E, int nbuck) {
    __shared__ int hist[MAXBUCK];
    int tid = threadIdx.x;
    long e0 = (long)blockIdx.x * CHUNK;
    for (int i = tid; i < nbuck; i += 256) hist[i] = 0;
    __syncthreads();
    int s[16], t[16];
#pragma unroll
    for (int it = 0; it < 16; ++it) {
        long e = e0 + it * 256 + tid;
        if (e < E) {
            s[it] = ei[e];
            t[it] = ei[E + e];
            atomicAdd(&hist[t[it] >> 8], 1);
        } else {
            s[it] = -1;
        }
    }
    __syncthreads();
    for (int i = tid; i < nbuck; i += 256) {
        int c = hist[i];
        hist[i] = c ? atomicAdd(&bcur[i], c) : 0;
    }
    __syncthreads();
#pragma unroll
    for (int it = 0; it < 16; ++it) {
        if (s[it] >= 0) {
            int b = t[it] >> 8;
            int p = atomicAdd(&hist[b], 1);
            binned[p] = ((unsigned)s[it] << 8) | (unsigned)(t[it] & 255);
        }
    }
}

// phase B: per-bucket LDS counting sort -> per-node CSR (adj, rowptr off, dinv)
__global__ void bucket_sort(const int* __restrict__ boff, const unsigned* __restrict__ binned,
                            int* __restrict__ off, int* __restrict__ adj,
                            float* __restrict__ dinv, int N, int E) {
    __shared__ int lcur[NPB];
    __shared__ int sh[NPB];
    int bid = blockIdx.x, tid = threadIdx.x;  // 256 threads
    int node0 = bid << 8;
    int e0 = boff[bid], e1 = boff[bid + 1];
    lcur[tid] = 0;
    __syncthreads();
    for (int e = e0 + tid; e < e1; e += 256)
        atomicAdd(&lcur[binned[e] & 255], 1);
    __syncthreads();
    int v = lcur[tid];
    sh[tid] = v;
    __syncthreads();
    for (int d = 1; d < NPB; d <<= 1) {
        int t = (tid >= d) ? sh[tid - d] : 0;
        __syncthreads();
        sh[tid] += t;
        __syncthreads();
    }
    int excl = sh[tid] - v;
    __syncthreads();
    lcur[tid] = excl;
    int node = node0 + tid;
    if (node < N) {
        off[node] = e0 + excl;
        dinv[node] = rsqrtf((float)v + 1.0f);
    }
    if (tid == 0 && bid == gridDim.x - 1) off[N] = E;
    __syncthreads();
    for (int e = e0 + tid; e < e1; e += 256) {
        unsigned u = binned[e];
        int p = atomicAdd(&lcur[u & 255], 1);
        adj[e0 + p] = (int)(u >> 8);
    }
}

// one wave per node; 2 edges per load instruction (bf16 rows), 8 loads in flight.
// lane = (sub = lane>>5 selects edge-of-pair, f = lane&31 selects feature pair)
__global__ void gather_agg(const int* __restrict__ off, const int* __restrict__ adj,
                           const unsigned* __restrict__ hb, const float* __restrict__ dinv,
                           const float2* __restrict__ x2, const float2* __restrict__ b2,
                           float2* __restrict__ o2, int N) {
    int node = blockIdx.x * 4 + (threadIdx.x >> 6);
    int lane = threadIdx.x & 63;
    if (node >= N) return;
    int sub = lane >> 5;     // which edge of the pair
    int f = lane & 31;       // feature-pair index (features 2f, 2f+1)
    int start = off[node];
    int m = off[node + 1] - start;
    float dn = dinv[node];
    float2 acc; acc.x = 0.f; acc.y = 0.f;

    for (int c = 0; c < m; c += 64) {
        int rem = m - c;
        int take = rem < 64 ? rem : 64;
        int s = (lane < take) ? adj[start + c + lane] : 0;
        float w = (lane < take) ? dinv[s] : 0.f;
        for (int i = 0; i < take; i += 16) {
            int i0 = i + 0 + sub,  i1 = i + 2 + sub,  i2 = i + 4 + sub,  i3 = i + 6 + sub;
            int i4 = i + 8 + sub,  i5 = i + 10 + sub, i6 = i + 12 + sub, i7 = i + 14 + sub;
            int t0 = __shfl(s, i0), t1 = __shfl(s, i1), t2 = __shfl(s, i2), t3 = __shfl(s, i3);
            int t4 = __shfl(s, i4), t5 = __shfl(s, i5), t6 = __shfl(s, i6), t7 = __shfl(s, i7);
            float q0 = __shfl(w, i0), q1 = __shfl(w, i1), q2 = __shfl(w, i2), q3 = __shfl(w, i3);
            float q4 = __shfl(w, i4), q5 = __shfl(w, i5), q6 = __shfl(w, i6), q7 = __shfl(w, i7);
            unsigned u0 = hb[(long)t0 * 32 + f];
            unsigned u1 = hb[(long)t1 * 32 + f];
            unsigned u2 = hb[(long)t2 * 32 + f];
            unsigned u3 = hb[(long)t3 * 32 + f];
            unsigned u4 = hb[(long)t4 * 32 + f];
            unsigned u5 = hb[(long)t5 * 32 + f];
            unsigned u6 = hb[(long)t6 * 32 + f];
            unsigned u7 = hb[(long)t7 * 32 + f];
            acc.x += __uint_as_float(u0 << 16) * q0;
            acc.y += __uint_as_float(u0 & 0xffff0000u) * q0;
            acc.x += __uint_as_float(u1 << 16) * q1;
            acc.y += __uint_as_float(u1 & 0xffff0000u) * q1;
            acc.x += __uint_as_float(u2 << 16) * q2;
            acc.y += __uint_as_float(u2 & 0xffff0000u) * q2;
            acc.x += __uint_as_float(u3 << 16) * q3;
            acc.y += __uint_as_float(u3 & 0xffff0000u) * q3;
            acc.x += __uint_as_float(u4 << 16) * q4;
            acc.y += __uint_as_float(u4 & 0xffff0000u) * q4;
            acc.x += __uint_as_float(u5 << 16) * q5;
            acc.y += __uint_as_float(u5 & 0xffff0000u) * q5;
            acc.x += __uint_as_float(u6 << 16) * q6;
            acc.y += __uint_as_float(u6 & 0xffff0000u) * q6;
            acc.x += __uint_as_float(u7 << 16) * q7;
            acc.y += __uint_as_float(u7 & 0xffff0000u) * q7;
        }
    }
    // merge the two half-wave edge sums (lane <-> lane^32)
    acc.x += __shfl_xor(acc.x, 32);
    acc.y += __shfl_xor(acc.y, 32);
    // self loop (post-merge, once)
    unsigned us = hb[(long)node * 32 + f];
    acc.x += __uint_as_float(us << 16) * dn;
    acc.y += __uint_as_float(us & 0xffff0000u) * dn;

    if (lane < 32) {
        long gi = (long)node * 32 + f;
        float2 bb = b2[f];
        float2 xx = x2[gi];
        float2 r;
        float vx = acc.x * dn + bb.x;
        float vy = acc.y * dn + bb.y;
        r.x = xx.x + fmaxf(vx, 0.f);
        r.y = xx.y + fmaxf(vy, 0.f);
        o2[gi] = r;
    }
}

extern "C" void kernel_launch(void* const* d_in, const int* in_sizes, int n_in,
                              void* d_out, int out_size, void* d_ws, size_t ws_size,
                              hipStream_t stream) {
    const float* x = (const float*)d_in[0];
    const int* ei  = (const int*)d_in[1];
    const float* W = (const float*)d_in[2];
    const float* b = (const float*)d_in[3];
    float* out = (float*)d_out;

    int N = in_sizes[0] / DIM;
    int E = in_sizes[1] / 2;
    int nbuck = (N + NPB - 1) / NPB;  // 391

    char* ws = (char*)d_ws;
    size_t o = 0;
    unsigned short* hbf = (unsigned short*)(ws + o); o += (size_t)N * DIM * sizeof(unsigned short);
    float* dinv  = (float*)(ws + o); o += (size_t)N * sizeof(float);
    int*   off   = (int*)(ws + o);   o += (size_t)(N + 1) * sizeof(int);
    int*   bcount= (int*)(ws + o);   o += (size_t)nbuck * sizeof(int);
    int*   boff  = (int*)(ws + o);   o += (size_t)(nbuck + 1) * sizeof(int);
    int*   bcur  = (int*)(ws + o);   o += (size_t)nbuck * sizeof(int);
    unsigned* binned = (unsigned*)(ws + o); o += (size_t)E * sizeof(unsigned);
    int*   adj   = (int*)(ws + o);   o += (size_t)E * sizeof(int);

    gcn_matmul<<<(N + 31) / 32, 256, 0, stream>>>(x, W, hbf, N);
    zero_i32<<<(nbuck + 255) / 256, 256, 0, stream>>>(bcount, nbuck);
    count_buckets<<<512, 256, 0, stream>>>(ei, bcount, E, nbuck);
    scan_buckets<<<1, MAXBUCK, 0, stream>>>(bcount, boff, bcur, nbuck, E);
    bin_edges<<<(E + CHUNK - 1) / CHUNK, 256, 0, stream>>>(ei, bcur, binned, E, nbuck);
    bucket_sort<<<nbuck, 256, 0, stream>>>(boff, binned, off, adj, dinv, N, E);
    gather_agg<<<(N + 3) / 4, 256, 0, stream>>>(off, adj, (const unsigned*)hbf, dinv,
                                                (const float2*)x, (const float2*)b,
                                                (float2*)out, N);
}